// Round 15
// baseline (258.129 us; speedup 1.0000x reference)
//
#include <hip/hip_runtime.h>
#include <cstdint>
#include <cstddef>

namespace {

constexpr int kS  = 2048;   // sequence
constexpr int kD  = 1024;   // model dim
constexpr int kHD = 64;     // head dim
constexpr int kTOK = 4096;  // B * S rows

typedef float f32x4 __attribute__((ext_vector_type(4)));
typedef __bf16 bf16x8 __attribute__((ext_vector_type(8)));
typedef unsigned short u16x8 __attribute__((ext_vector_type(8)));

__device__ __forceinline__ unsigned short f2b(float f){
  unsigned int u = __builtin_bit_cast(unsigned int, f);
  u += 0x7fffu + ((u >> 16) & 1u);      // RNE
  return (unsigned short)(u >> 16);
}

__device__ __forceinline__ float b2f(unsigned short u){
  return __builtin_bit_cast(float, (unsigned)u << 16);
}

__device__ __forceinline__ bf16x8 ldfrag(const unsigned short* p){
  return __builtin_bit_cast(bf16x8, *(const u16x8*)p);
}

__device__ __forceinline__ float fexp2(float x){
#if __has_builtin(__builtin_amdgcn_exp2f)
  return __builtin_amdgcn_exp2f(x);
#else
  return exp2f(x);
#endif
}

// erf via Abramowitz-Stegun 7.1.26 (|eps| <= 1.5e-7, far below bf16 resolution)
__device__ __forceinline__ float fast_erf(float x){
  const float ax = fabsf(x);
#if __has_builtin(__builtin_amdgcn_rcpf)
  const float t = __builtin_amdgcn_rcpf(1.0f + 0.3275911f * ax);
#else
  const float t = 1.0f / (1.0f + 0.3275911f * ax);
#endif
  const float y = t * (0.254829592f + t * (-0.284496736f + t * (1.421413741f +
                  t * (-1.453152027f + t * 1.061405429f))));
  const float e = fexp2(-ax * ax * 1.4426950408889634f);
  return copysignf(1.0f - y * e, x);
}

__device__ __forceinline__ void gl_lds16(const void* g, void* l){
  // async global->LDS, 16B per lane; LDS dest is wave-uniform base + lane*16
  __builtin_amdgcn_global_load_lds(
      (__attribute__((address_space(1))) void*)(void*)g,
      (__attribute__((address_space(3))) void*)l, 16, 0, 0);
}

// swizzled 16B fragment read from a 64-col bf16 tile: slot in [0,8)
__device__ __forceinline__ bf16x8 ld_swz(const unsigned short* tile, int row, int slot){
  return ldfrag(tile + row * 64 + (((slot ^ row) & 7) << 3));
}

// 512-thread staging of one 64-row K tile from fused QKV (head-block mapping)
__device__ __forceinline__ void stageK8(const unsigned short* Kg, unsigned short* lds,
                                        int tid, int t0){
  const int r = tid >> 3, sl = tid & 7;        // row 0..63, 16B slot 0..7
  const int sabs = t0 + r;
  gl_lds16(Kg + (size_t)(sabs >> 4) * 3072 + (sabs & 15) * 64 + (((sl ^ r) & 7) << 3),
           (char*)lds + tid * 16);
}

// 512-thread staging of a 64x64 slice of Vt [64][kS] (cols t0..t0+64)
__device__ __forceinline__ void stageV8(const unsigned short* Vh, unsigned short* lds,
                                        int tid, int t0){
  const int r = tid >> 3, sl = tid & 7;
  gl_lds16(Vh + (size_t)r * kS + t0 + (((sl ^ r) & 7) << 3),
           (char*)lds + tid * 16);
}

// ---------- merged misc preamble: cvt (4096 blk) | maskbits (16384) | catbias (12)
__global__ __launch_bounds__(256) void prep_misc_kern(const float* __restrict__ x,
                                                      unsigned short* __restrict__ xb,
                                                      const int* __restrict__ mask,
                                                      unsigned long long* __restrict__ mb,
                                                      const float* __restrict__ bq,
                                                      const float* __restrict__ bk,
                                                      const float* __restrict__ bv,
                                                      float* __restrict__ bqkv){
  const int b = blockIdx.x;
  if (b < 4096){
    const int i = b * 256 + threadIdx.x;
    float4 v = ((const float4*)x)[i];
    ((ushort4*)xb)[i] = make_ushort4(f2b(v.x), f2b(v.y), f2b(v.z), f2b(v.w));
  } else if (b < 20480){
    const int gw   = ((b - 4096) * 256 + threadIdx.x) >> 6;
    const int lane = threadIdx.x & 63;
    const int row  = gw >> 5, word = gw & 31;
    const int key  = ((lane >> 2) & 3) * 16 + ((lane >> 4) & 3) * 4 + (lane & 3);
    const int m = mask[(size_t)row * kS + word * 64 + key];
    const unsigned long long bl = __ballot(m != 0);
    if (lane == 0) mb[(size_t)row * 32 + word] = bl;
  } else {
    const int i = (b - 20480) * 256 + threadIdx.x;
    float v = (i < 1024) ? bq[i] : ((i < 2048) ? bk[i - 1024] : bv[i - 2048]);
    bqkv[i] = v;
  }
}

// ---------- merged weight transposes: 6 jobs by block range --------------------
__global__ __launch_bounds__(256) void wtrans_all_kern(const float* __restrict__ Wq,
                                                       const float* __restrict__ Wk,
                                                       const float* __restrict__ Wv,
                                                       const float* __restrict__ Wo,
                                                       const float* __restrict__ W1,
                                                       const float* __restrict__ W2,
                                                       unsigned short* __restrict__ WqkvT,
                                                       unsigned short* __restrict__ WoT,
                                                       unsigned short* __restrict__ W1T,
                                                       unsigned short* __restrict__ W2T){
  const int b = blockIdx.x;
  const float* W; unsigned short* Wt; int K, N, nx, lb;
  if      (b < 1024){ W = Wq; Wt = WqkvT;                 K = 1024; N = 1024; nx = 32;  lb = b; }
  else if (b < 2048){ W = Wk; Wt = WqkvT + 1024 * 1024;   K = 1024; N = 1024; nx = 32;  lb = b - 1024; }
  else if (b < 3072){ W = Wv; Wt = WqkvT + 2048 * 1024;   K = 1024; N = 1024; nx = 32;  lb = b - 2048; }
  else if (b < 4096){ W = Wo; Wt = WoT;                   K = 1024; N = 1024; nx = 32;  lb = b - 3072; }
  else if (b < 8192){ W = W1; Wt = W1T;                   K = 1024; N = 4096; nx = 128; lb = b - 4096; }
  else              { W = W2; Wt = W2T;                   K = 4096; N = 1024; nx = 32;  lb = b - 8192; }
  __shared__ float t[32][33];
  const int n0 = (lb % nx) * 32, k0 = (lb / nx) * 32;
  const int tx = threadIdx.x & 31, ty = threadIdx.x >> 5;   // ty in [0,8)
  #pragma unroll
  for (int i = 0; i < 32; i += 8)
    t[ty + i][tx] = W[(size_t)(k0 + ty + i) * N + n0 + tx];
  __syncthreads();
  #pragma unroll
  for (int i = 0; i < 32; i += 8)
    Wt[(size_t)(n0 + ty + i) * K + k0 + tx] = f2b(t[tx][ty + i]);
}

// ---------------- V slice of fused QKV -> Vt [bh][64][kS] (bf16 transpose) -------
__global__ __launch_bounds__(256) void vtrans_kern(const unsigned short* __restrict__ QKV,
                                                   unsigned short* __restrict__ Vt){
  __shared__ unsigned short t[64][65];
  int bh = blockIdx.y, s0 = blockIdx.x * 64;
  const int rowbase = (bh >> 4) * 2048 + (bh & 15) * 128;
  const unsigned short* Vg = QKV + (size_t)rowbase * 3072 + 2048;
  unsigned short* Vth = Vt + (size_t)bh * kHD * kS;
  int tx = threadIdx.x & 63, ty = threadIdx.x >> 6;   // ty in [0,4)
  #pragma unroll
  for (int i = 0; i < 64; i += 4){
    const int s = s0 + ty + i;
    t[ty + i][tx] = Vg[(size_t)(s >> 4) * 3072 + (s & 15) * 64 + tx];
  }
  __syncthreads();
  #pragma unroll
  for (int i = 0; i < 64; i += 4)
    Vth[(size_t)(ty + i) * kS + s0 + tx] = t[tx][ty + i];
}

// ================= GEMM v8: 128x128 tile, BK=64, 4 waves, 2 blocks/CU ===========
// Structure-matched tile choice (m97/m103: 128^2 is the optimum for simple
// 2-barrier loops; 256^2 needs the full 8-phase interleave). 64 KB LDS ->
// 2 independent blocks/CU restore implicit wave overlap across barriers (m114).
// Counted vmcnt, never drains mid-loop. Ledger (8 loads per K-tile stage):
//   prologue: stage tile0 (8), vmcnt(0), barrier.
//   iter t: stage tile t+1 (outstanding 16) -> vmcnt(8) lands tile t exactly;
//           reads buf[t&1]; 32 MFMA; barrier (separates reads of buf[t&1]
//           from iter t+1's stage into that same buffer).
//   last iter: vmcnt(0), no stage, no barrier.
template <int ACT_GELU, int SPLITK, int SCLQ>
__global__ __launch_bounds__(256, 2) void gemm128_kern(const unsigned short* __restrict__ A,
                                                       const unsigned short* __restrict__ Bt,
                                                       const float* __restrict__ bias,
                                                       unsigned short* __restrict__ C,
                                                       int M, int N, int K){
  __shared__ unsigned short As[2][128 * 64];
  __shared__ unsigned short Bs[2][128 * 64];
  int bid = blockIdx.y * gridDim.x + blockIdx.x;
  const int nwg = gridDim.x * gridDim.y;
  bid = (bid & 7) * (nwg >> 3) + (bid >> 3);            // T1 XCD swizzle (nwg%8==0)
  const int bx = bid % gridDim.x, by = bid / gridDim.x;
  const int m0 = by << 7, n0 = bx << 7;
  const int tid  = threadIdx.x;
  const int wave = tid >> 6, lane = tid & 63;
  const int wr = wave >> 1, wc = wave & 1;              // 2 x 2 wave grid
  const int lr = lane & 15, lk = lane >> 4;
  const int kz   = K / SPLITK;
  const int kbeg = (SPLITK > 1) ? blockIdx.z * kz : 0;
  const int NT   = kz >> 6;                             // K-tiles of 64
  const int srow = tid >> 3;                            // 0..31 (+32 per call)
  const int scol = ((tid & 7) ^ (srow & 7)) << 3;       // inverse-swizzled src slot
  const unsigned short* Ag = A  + (size_t)(m0 + srow) * K + kbeg + scol;
  const unsigned short* Bg = Bt + (size_t)(n0 + srow) * K + kbeg + scol;
  const int dst = tid * 8;                              // ushorts; +2048/call
  const int sk0 = ((    lk) ^ (lr & 7)) << 3;           // kk=0 swizzled slot
  const int sk1 = ((4 + lk) ^ (lr & 7)) << 3;           // kk=1
  const int aro = (wr * 64 + lr) * 64;
  const int bro = (wc * 64 + lr) * 64;

  f32x4 acc[4][4] = {};

  auto stage = [&](int b, int kt){
    const unsigned short* a = Ag + (size_t)kt * 64;
    const unsigned short* g = Bg + (size_t)kt * 64;
    #pragma unroll
    for (int i = 0; i < 4; ++i)
      gl_lds16(a + (size_t)(i * 32) * K, &As[b][i * 2048 + dst]);
    #pragma unroll
    for (int i = 0; i < 4; ++i)
      gl_lds16(g + (size_t)(i * 32) * K, &Bs[b][i * 2048 + dst]);
  };

  // prologue
  stage(0, 0);
  asm volatile("s_waitcnt vmcnt(0)" ::: "memory");
  asm volatile("s_barrier" ::: "memory");

  for (int t = 0; t < NT; ++t){
    const int b = t & 1;
    const bool pf = (t + 1 < NT);
    if (pf){ stage(b ^ 1, t + 1); asm volatile("s_waitcnt vmcnt(8)" ::: "memory"); }
    else   {                      asm volatile("s_waitcnt vmcnt(0)" ::: "memory"); }
    bf16x8 aR[4][2], bR[4][2];
    #pragma unroll
    for (int m = 0; m < 4; ++m){
      aR[m][0] = ldfrag(&As[b][aro + m * 1024 + sk0]);
      aR[m][1] = ldfrag(&As[b][aro + m * 1024 + sk1]);
    }
    #pragma unroll
    for (int n = 0; n < 4; ++n){
      bR[n][0] = ldfrag(&Bs[b][bro + n * 1024 + sk0]);
      bR[n][1] = ldfrag(&Bs[b][bro + n * 1024 + sk1]);
    }
    __builtin_amdgcn_s_setprio(1);
    #pragma unroll
    for (int kk = 0; kk < 2; ++kk)
      #pragma unroll
      for (int m = 0; m < 4; ++m)
        #pragma unroll
        for (int n = 0; n < 4; ++n)
          acc[m][n] = __builtin_amdgcn_mfma_f32_16x16x32_bf16(
              aR[m][kk], bR[n][kk], acc[m][n], 0, 0, 0);
    __builtin_amdgcn_s_setprio(0);
    if (pf) asm volatile("s_barrier" ::: "memory");
  }

  unsigned short* Cb = C + (SPLITK > 1 ? (size_t)blockIdx.z * M * N : 0);
  float bvv[4], csc[4];
  #pragma unroll
  for (int n = 0; n < 4; ++n){
    const int col = n0 + wc * 64 + n * 16 + lr;
    bvv[n] = (SPLITK == 1) ? bias[col] : 0.0f;
    csc[n] = (SCLQ && col < 1024) ? 0.18033688011112042f : 1.0f;
  }
  #pragma unroll
  for (int m = 0; m < 4; ++m){
    #pragma unroll
    for (int j = 0; j < 4; ++j){
      const int row = m0 + wr * 64 + m * 16 + lk * 4 + j;
      unsigned short* crow = Cb + (size_t)row * N + n0 + wc * 64 + lr;
      #pragma unroll
      for (int n = 0; n < 4; ++n){          // n-inner: 4 adjacent half-line stores
        float v = acc[m][n][j] + bvv[n];
        if (ACT_GELU) v = 0.5f * v * (1.0f + fast_erf(v * 0.70710678118654752f));
        if (SCLQ) v *= csc[n];
        crow[n * 16] = f2b(v);
      }
    }
  }
}

// ===== flash attention v8 (FROZEN): R11 compute + T4 counted-vmcnt 3-buffer =====
__global__ __launch_bounds__(512) void attn_kern(const unsigned short* __restrict__ QKV,
                                                 const unsigned short* __restrict__ Vt,
                                                 const unsigned long long* __restrict__ mbits,
                                                 unsigned short* __restrict__ O){
  __shared__ unsigned short Ks[3][64 * 64];
  __shared__ unsigned short Vs[3][64 * 64];     // [d][t], swizzled
  __shared__ unsigned short Ps[8][16 * 64];     // per-wave P [qrow][key], swizzled
  const int tid = threadIdx.x;
  const int wave = tid >> 6, lane = tid & 63;
  const int lr = lane & 15, lk = lane >> 4;
  // T1 XCD swizzle: nwg = 16*32 = 512; each XCD gets 64 consecutive bids = 4 heads
  int bid = blockIdx.y * gridDim.x + blockIdx.x;
  bid = (bid & 7) * 64 + (bid >> 3);
  const int qblk = bid & 15, bh = bid >> 4;
  const int rowbase = (bh >> 4) * 2048 + (bh & 15) * 128;
  const unsigned short* Qg = QKV + (size_t)rowbase * 3072;
  const unsigned short* Kg = Qg + 1024;
  const unsigned short* Vh = Vt + (size_t)bh * kHD * kS;
  const int qbase = qblk * 128 + wave * 16;
  constexpr int NT = kS / 64;   // 32

  // Q (pre-scaled by 0.125*log2e in the QKV epilogue) as MFMA B-fragment
  bf16x8 qf[2];
  { const int qr = qbase + lr;
    const unsigned short* qp = Qg + (size_t)(qr >> 4) * 3072 + (qr & 15) * 64 + lk * 8;
    qf[0] = ldfrag(qp); qf[1] = ldfrag(qp + 32); }

  f32x4 accO[4] = {};
  float lsum = 0.f;
  unsigned short* Pw = Ps[wave];
  char* Pwb = (char*)Pw + lr * 128 + ((lk & 1) << 3);
  const int lr7 = lr & 7;

  const unsigned long long* mrp = mbits + (size_t)(qbase + lr) * 32;
  unsigned long long mb = mrp[0];

  // prologue: stage tiles 0 and 1; land tile 0 (leave K1,V1 in flight)
  stageK8(Kg, Ks[0], tid, 0);
  stageV8(Vh, Vs[0], tid, 0);
  stageK8(Kg, Ks[1], tid, 64);
  stageV8(Vh, Vs[1], tid, 64);
  asm volatile("s_waitcnt vmcnt(2)" ::: "memory");
  asm volatile("s_barrier" ::: "memory");

  int cur = 0, stg = 2;
  for (int t = 0; t < NT; ++t){
    unsigned long long mbn = 0;
    if (t < NT - 1) mbn = mrp[t + 1];
    if (t < NT - 2){
      stageK8(Kg, Ks[stg], tid, (t + 2) * 64);
      stageV8(Vh, Vs[stg], tid, (t + 2) * 64);
    }
    // QK^T swapped: sa[n][j] = S[key = n*16 + lk*4 + j][qrow = lr] (pre-scaled)
    f32x4 sa[4] = {};
    #pragma unroll
    for (int kk = 0; kk < 2; ++kk)
      #pragma unroll
      for (int n = 0; n < 4; ++n){
        bf16x8 kf = ld_swz(Ks[cur], n * 16 + lr, kk * 4 + lk);
        sa[n] = __builtin_amdgcn_mfma_f32_16x16x32_bf16(kf, qf[kk], sa[n], 0, 0, 0);
      }
    const unsigned wb = (unsigned)(mb >> (lk * 16));
    float s = 0.f;
    #pragma unroll
    for (int n = 0; n < 4; ++n){
      float p0, p1, p2, p3;
      {
        float v0 = fexp2(sa[n][0]), v1 = fexp2(sa[n][1]);
        float v2 = fexp2(sa[n][2]), v3 = fexp2(sa[n][3]);
        const int s0 = ((int)(wb << (31 - (n * 4 + 0)))) >> 31;
        const int s1 = ((int)(wb << (31 - (n * 4 + 1)))) >> 31;
        const int s2 = ((int)(wb << (31 - (n * 4 + 2)))) >> 31;
        const int s3 = ((int)(wb << (31 - (n * 4 + 3)))) >> 31;
        p0 = __builtin_bit_cast(float, __builtin_bit_cast(int, v0) & s0);
        p1 = __builtin_bit_cast(float, __builtin_bit_cast(int, v1) & s1);
        p2 = __builtin_bit_cast(float, __builtin_bit_cast(int, v2) & s2);
        p3 = __builtin_bit_cast(float, __builtin_bit_cast(int, v3) & s3);
      }
      s += (p0 + p1) + (p2 + p3);
      unsigned r0, r1;
      asm("v_cvt_pk_bf16_f32 %0, %1, %2" : "=v"(r0) : "v"(p0), "v"(p1));
      asm("v_cvt_pk_bf16_f32 %0, %1, %2" : "=v"(r1) : "v"(p2), "v"(p3));
      *(uint2*)(Pwb + (((2 * n + (lk >> 1)) ^ lr7) << 4)) = make_uint2(r0, r1);
    }
    s += __shfl_xor(s, 16);
    s += __shfl_xor(s, 32);
    lsum += s;
    #pragma unroll
    for (int kk = 0; kk < 2; ++kk){
      bf16x8 pf = ld_swz(Pw, lr, kk * 4 + lk);
      #pragma unroll
      for (int dd = 0; dd < 4; ++dd){
        bf16x8 vfr = ld_swz(Vs[cur], dd * 16 + lr, kk * 4 + lk);
        accO[dd] = __builtin_amdgcn_mfma_f32_16x16x32_bf16(pf, vfr, accO[dd], 0, 0, 0);
      }
    }
    mb = mbn;
    if (t < NT - 2){
      asm volatile("s_waitcnt vmcnt(3)" ::: "memory");   // lands K,V(t+1)
    } else if (t < NT - 1){
      asm volatile("s_waitcnt vmcnt(1)" ::: "memory");   // lands K,V(NT-1)
    }
    if (t < NT - 1) asm volatile("s_barrier" ::: "memory");
    cur = (cur == 2) ? 0 : cur + 1;
    stg = (stg == 2) ? 0 : stg + 1;
  }
  const size_t hoff = (size_t)bh * kS * kHD;
  #pragma unroll
  for (int j = 0; j < 4; ++j){
    const float inv = 1.0f / __shfl(lsum, lk * 4 + j);
    const int row = qbase + lk * 4 + j;
    #pragma unroll
    for (int dd = 0; dd < 4; ++dd)
      O[hoff + (size_t)row * 64 + dd * 16 + lr] = f2b(accO[dd][j] * inv);
  }
}

// ------- fused split-K reduce + bias + residual add + LayerNorm -----------------
template <int NP, int PBF16, int OUT_B>
__global__ __launch_bounds__(256) void add_ln_kern(const float* __restrict__ X,
                                                   const void* __restrict__ P,
                                                   const float* __restrict__ bias,
                                                   const float* __restrict__ g,
                                                   const float* __restrict__ be,
                                                   float* __restrict__ Yf,
                                                   unsigned short* __restrict__ Yb){
  const int row = blockIdx.x;
  const int tid = threadIdx.x;
  const size_t pstride = (size_t)kTOK * kD;
  const int idx = row * 256 + tid;
  float r0 = 0.f, r1 = 0.f, r2 = 0.f, r3 = 0.f;
  #pragma unroll
  for (int z = 0; z < NP; ++z){
    if (PBF16){
      ushort4 u = ((const ushort4*)P)[z * (pstride / 4) + idx];
      r0 += b2f(u.x); r1 += b2f(u.y); r2 += b2f(u.z); r3 += b2f(u.w);
    } else {
      float4 p = ((const float4*)P)[z * (pstride / 4) + idx];
      r0 += p.x; r1 += p.y; r2 += p.z; r3 += p.w;
    }
  }
  const float4 bb = ((const float4*)bias)[tid];
  const float4 xv = ((const float4*)X)[idx];
  const float a0 = xv.x + r0 + bb.x, a1 = xv.y + r1 + bb.y;
  const float a2 = xv.z + r2 + bb.z, a3 = xv.w + r3 + bb.w;
  float s = a0 + a1 + a2 + a3;
  float q = a0*a0 + a1*a1 + a2*a2 + a3*a3;
  #pragma unroll
  for (int d = 1; d < 64; d <<= 1){ s += __shfl_xor(s, d); q += __shfl_xor(q, d); }
  __shared__ float red[8];
  const int wave = tid >> 6, lane = tid & 63;
  if (lane == 0){ red[wave] = s; red[4 + wave] = q; }
  __syncthreads();
  s = red[0] + red[1] + red[2] + red[3];
  q = red[4] + red[5] + red[6] + red[7];
  const float mu   = s * (1.0f / kD);
  const float var  = q * (1.0f / kD) - mu * mu;
  const float rstd = rsqrtf(var + 1e-5f);
  const float4 gv = ((const float4*)g)[tid];
  const float4 bv = ((const float4*)be)[tid];
  const float y0 = (a0 - mu) * rstd * gv.x + bv.x;
  const float y1 = (a1 - mu) * rstd * gv.y + bv.y;
  const float y2 = (a2 - mu) * rstd * gv.z + bv.z;
  const float y3 = (a3 - mu) * rstd * gv.w + bv.w;
  ((float4*)Yf)[idx] = make_float4(y0, y1, y2, y3);
  if (OUT_B)
    ((ushort4*)Yb)[idx] = make_ushort4(f2b(y0), f2b(y1), f2b(y2), f2b(y3));
}

} // namespace

extern "C" void kernel_launch(void* const* d_in, const int* in_sizes, int n_in,
                              void* d_out, int out_size, void* d_ws, size_t ws_size,
                              hipStream_t stream){
  (void)in_sizes; (void)n_in; (void)out_size;
  const float* x   = (const float*)d_in[0];
  const int*   mask= (const int*)d_in[1];
  const float* Wq  = (const float*)d_in[2];  const float* bq  = (const float*)d_in[3];
  const float* Wk  = (const float*)d_in[4];  const float* bk  = (const float*)d_in[5];
  const float* Wv  = (const float*)d_in[6];  const float* bv  = (const float*)d_in[7];
  const float* Wo  = (const float*)d_in[8];  const float* bo  = (const float*)d_in[9];
  const float* W1  = (const float*)d_in[10]; const float* b1  = (const float*)d_in[11];
  const float* W2  = (const float*)d_in[12]; const float* b2  = (const float*)d_in[13];
  const float* g1  = (const float*)d_in[14]; const float* be1 = (const float*)d_in[15];
  const float* g2  = (const float*)d_in[16]; const float* be2 = (const float*)d_in[17];

  char* ws = (char*)d_ws;
  const size_t MB = 1024 * 1024;
  if (ws_size < 96 * MB) return;   // need 96 MB of scratch

  // Layout (stage-by-stage lifetime-checked):
  unsigned short* W2T   = (unsigned short*)(ws + 0 * MB);    //  8 MB  preamble -> W2
  unsigned short* W1T   = (unsigned short*)(ws + 8 * MB);    //  8 MB  preamble -> W1
  unsigned short* WqkvT = (unsigned short*)(ws + 16 * MB);   //  6 MB  preamble -> QKV
  unsigned short* WoT   = (unsigned short*)(ws + 22 * MB);   //  2 MB  preamble -> Wo
  unsigned short* xb    = (unsigned short*)(ws + 24 * MB);   //  8 MB  preamble -> QKV
  unsigned short* qkv   = (unsigned short*)(ws + 32 * MB);   // 24 MB  QKV -> attn
  unsigned short* vt    = (unsigned short*)(ws + 56 * MB);   //  8 MB  vtrans -> attn
  unsigned short* av    = (unsigned short*)(ws + 64 * MB);   //  8 MB  attn -> Wo
  unsigned long long* mbits = (unsigned long long*)(ws + 72 * MB);     // 512 KB -> attn
  float* bqkv           = (float*)(ws + 80 * MB);            // 12 KB  preamble -> QKV
  // aliases (lifetimes checked): mbits/bqkv dead after attn/QKV respectively.
  unsigned short* woP   = (unsigned short*)(ws + 32 * MB);   // 32 MB [4][4096][1024] bf16, Wo -> LN1
  float* y32            = (float*)(ws + 72 * MB);            // 16 MB LN1 -> LN2 (over mbits+bqkv, dead)
  unsigned short* yb    = (unsigned short*)(ws + 88 * MB);   //  8 MB LN1 -> W1
  unsigned short* hb    = (unsigned short*)(ws + 40 * MB);   // 32 MB W1 -> W2 (over woP tail+vt+av, dead)
  unsigned short* w2p   = (unsigned short*)(ws + 8 * MB);    // 32 MB [4][4096][1024] bf16, W2 -> LN2

  dim3 blk(256), gblk(512);
  wtrans_all_kern<<<dim3(12288), blk, 0, stream>>>(Wq, Wk, Wv, Wo, W1, W2,
                                                   WqkvT, WoT, W1T, W2T);
  prep_misc_kern<<<dim3(20492), blk, 0, stream>>>(x, xb, mask, mbits, bq, bk, bv, bqkv);

  // fused QKV projection: [4096][3072]; Q columns pre-scaled by 0.125*log2(e)
  gemm128_kern<0,1,1><<<dim3(24, 32), blk, 0, stream>>>(xb, WqkvT, bqkv, qkv, 4096, 3072, 1024);

  vtrans_kern<<<dim3(32, 32), blk, 0, stream>>>(qkv, vt);
  attn_kern<<<dim3(16, 32), gblk, 0, stream>>>(qkv, vt, mbits, av);

  // Wo projection, split-K x4 -> bf16 partials; LN1 fuses reduce + bo + residual(x)
  gemm128_kern<0,4,0><<<dim3(8, 32, 4), blk, 0, stream>>>(av, WoT, bo, woP, 4096, 1024, 1024);
  add_ln_kern<4,1,1><<<dim3(4096), blk, 0, stream>>>(x, woP, bo, g1, be1, y32, yb);

  // FFN
  gemm128_kern<1,1,0><<<dim3(32, 32), blk, 0, stream>>>(yb, W1T, b1, hb, 4096, 4096, 1024);
  // W2, split-K x4 -> bf16 partials; LN2 fuses reduce + b2 + residual(y32)
  gemm128_kern<0,4,0><<<dim3(8, 32, 4), blk, 0, stream>>>(hb, W2T, b2, w2p, 4096, 1024, 4096);
  add_ln_kern<4,1,0><<<dim3(4096), blk, 0, stream>>>(y32, w2p, b2, g2, be2, (float*)d_out, nullptr);
}

// Round 17
// 235.342 us; speedup vs baseline: 1.0968x; 1.0968x over previous
//
#include <hip/hip_runtime.h>
#include <cstdint>
#include <cstddef>

namespace {

constexpr int kS  = 2048;   // sequence
constexpr int kD  = 1024;   // model dim
constexpr int kHD = 64;     // head dim
constexpr int kTOK = 4096;  // B * S rows

typedef float f32x4 __attribute__((ext_vector_type(4)));
typedef __bf16 bf16x8 __attribute__((ext_vector_type(8)));
typedef unsigned short u16x8 __attribute__((ext_vector_type(8)));

__device__ __forceinline__ unsigned short f2b(float f){
  unsigned int u = __builtin_bit_cast(unsigned int, f);
  u += 0x7fffu + ((u >> 16) & 1u);      // RNE
  return (unsigned short)(u >> 16);
}

__device__ __forceinline__ float b2f(unsigned short u){
  return __builtin_bit_cast(float, (unsigned)u << 16);
}

__device__ __forceinline__ bf16x8 ldfrag(const unsigned short* p){
  return __builtin_bit_cast(bf16x8, *(const u16x8*)p);
}

__device__ __forceinline__ float fexp2(float x){
#if __has_builtin(__builtin_amdgcn_exp2f)
  return __builtin_amdgcn_exp2f(x);
#else
  return exp2f(x);
#endif
}

// erf via Abramowitz-Stegun 7.1.26 (|eps| <= 1.5e-7, far below bf16 resolution)
__device__ __forceinline__ float fast_erf(float x){
  const float ax = fabsf(x);
#if __has_builtin(__builtin_amdgcn_rcpf)
  const float t = __builtin_amdgcn_rcpf(1.0f + 0.3275911f * ax);
#else
  const float t = 1.0f / (1.0f + 0.3275911f * ax);
#endif
  const float y = t * (0.254829592f + t * (-0.284496736f + t * (1.421413741f +
                  t * (-1.453152027f + t * 1.061405429f))));
  const float e = fexp2(-ax * ax * 1.4426950408889634f);
  return copysignf(1.0f - y * e, x);
}

__device__ __forceinline__ void gl_lds16(const void* g, void* l){
  // async global->LDS, 16B per lane; LDS dest is wave-uniform base + lane*16
  __builtin_amdgcn_global_load_lds(
      (__attribute__((address_space(1))) void*)(void*)g,
      (__attribute__((address_space(3))) void*)l, 16, 0, 0);
}

// swizzled 16B fragment read from a 64-col bf16 tile: slot in [0,8)
__device__ __forceinline__ bf16x8 ld_swz(const unsigned short* tile, int row, int slot){
  return ldfrag(tile + row * 64 + (((slot ^ row) & 7) << 3));
}

// 512-thread staging of one 64-row K tile from fused QKV (head-block mapping)
__device__ __forceinline__ void stageK8(const unsigned short* Kg, unsigned short* lds,
                                        int tid, int t0){
  const int r = tid >> 3, sl = tid & 7;        // row 0..63, 16B slot 0..7
  const int sabs = t0 + r;
  gl_lds16(Kg + (size_t)(sabs >> 4) * 3072 + (sabs & 15) * 64 + (((sl ^ r) & 7) << 3),
           (char*)lds + tid * 16);
}

// 512-thread staging of a 64x64 slice of Vt [64][kS] (cols t0..t0+64)
__device__ __forceinline__ void stageV8(const unsigned short* Vh, unsigned short* lds,
                                        int tid, int t0){
  const int r = tid >> 3, sl = tid & 7;
  gl_lds16(Vh + (size_t)r * kS + t0 + (((sl ^ r) & 7) << 3),
           (char*)lds + tid * 16);
}

// ---------- merged misc preamble: cvt (4096 blk) | maskbits (16384) | catbias (12)
__global__ __launch_bounds__(256) void prep_misc_kern(const float* __restrict__ x,
                                                      unsigned short* __restrict__ xb,
                                                      const int* __restrict__ mask,
                                                      unsigned long long* __restrict__ mb,
                                                      const float* __restrict__ bq,
                                                      const float* __restrict__ bk,
                                                      const float* __restrict__ bv,
                                                      float* __restrict__ bqkv){
  const int b = blockIdx.x;
  if (b < 4096){
    const int i = b * 256 + threadIdx.x;
    float4 v = ((const float4*)x)[i];
    ((ushort4*)xb)[i] = make_ushort4(f2b(v.x), f2b(v.y), f2b(v.z), f2b(v.w));
  } else if (b < 20480){
    const int gw   = ((b - 4096) * 256 + threadIdx.x) >> 6;
    const int lane = threadIdx.x & 63;
    const int row  = gw >> 5, word = gw & 31;
    const int key  = ((lane >> 2) & 3) * 16 + ((lane >> 4) & 3) * 4 + (lane & 3);
    const int m = mask[(size_t)row * kS + word * 64 + key];
    const unsigned long long bl = __ballot(m != 0);
    if (lane == 0) mb[(size_t)row * 32 + word] = bl;
  } else {
    const int i = (b - 20480) * 256 + threadIdx.x;
    float v = (i < 1024) ? bq[i] : ((i < 2048) ? bk[i - 1024] : bv[i - 2048]);
    bqkv[i] = v;
  }
}

// ---------- merged weight transposes: 6 jobs by block range --------------------
__global__ __launch_bounds__(256) void wtrans_all_kern(const float* __restrict__ Wq,
                                                       const float* __restrict__ Wk,
                                                       const float* __restrict__ Wv,
                                                       const float* __restrict__ Wo,
                                                       const float* __restrict__ W1,
                                                       const float* __restrict__ W2,
                                                       unsigned short* __restrict__ WqkvT,
                                                       unsigned short* __restrict__ WoT,
                                                       unsigned short* __restrict__ W1T,
                                                       unsigned short* __restrict__ W2T){
  const int b = blockIdx.x;
  const float* W; unsigned short* Wt; int K, N, nx, lb;
  if      (b < 1024){ W = Wq; Wt = WqkvT;                 K = 1024; N = 1024; nx = 32;  lb = b; }
  else if (b < 2048){ W = Wk; Wt = WqkvT + 1024 * 1024;   K = 1024; N = 1024; nx = 32;  lb = b - 1024; }
  else if (b < 3072){ W = Wv; Wt = WqkvT + 2048 * 1024;   K = 1024; N = 1024; nx = 32;  lb = b - 2048; }
  else if (b < 4096){ W = Wo; Wt = WoT;                   K = 1024; N = 1024; nx = 32;  lb = b - 3072; }
  else if (b < 8192){ W = W1; Wt = W1T;                   K = 1024; N = 4096; nx = 128; lb = b - 4096; }
  else              { W = W2; Wt = W2T;                   K = 4096; N = 1024; nx = 32;  lb = b - 8192; }
  __shared__ float t[32][33];
  const int n0 = (lb % nx) * 32, k0 = (lb / nx) * 32;
  const int tx = threadIdx.x & 31, ty = threadIdx.x >> 5;   // ty in [0,8)
  #pragma unroll
  for (int i = 0; i < 32; i += 8)
    t[ty + i][tx] = W[(size_t)(k0 + ty + i) * N + n0 + tx];
  __syncthreads();
  #pragma unroll
  for (int i = 0; i < 32; i += 8)
    Wt[(size_t)(n0 + ty + i) * K + k0 + tx] = f2b(t[tx][ty + i]);
}

// ---------------- V slice of fused QKV -> Vt [bh][64][kS] (bf16 transpose) -------
__global__ __launch_bounds__(256) void vtrans_kern(const unsigned short* __restrict__ QKV,
                                                   unsigned short* __restrict__ Vt){
  __shared__ unsigned short t[64][65];
  int bh = blockIdx.y, s0 = blockIdx.x * 64;
  const int rowbase = (bh >> 4) * 2048 + (bh & 15) * 128;
  const unsigned short* Vg = QKV + (size_t)rowbase * 3072 + 2048;
  unsigned short* Vth = Vt + (size_t)bh * kHD * kS;
  int tx = threadIdx.x & 63, ty = threadIdx.x >> 6;   // ty in [0,4)
  #pragma unroll
  for (int i = 0; i < 64; i += 4){
    const int s = s0 + ty + i;
    t[ty + i][tx] = Vg[(size_t)(s >> 4) * 3072 + (s & 15) * 64 + tx];
  }
  __syncthreads();
  #pragma unroll
  for (int i = 0; i < 64; i += 4)
    Vth[(size_t)(ty + i) * kS + s0 + tx] = t[tx][ty + i];
}

// ================= GEMM v7 (R14 verified): 256x256, BK=64, 4-phase schedule =====
// m201-style wait discipline: vmcnt(4) ONLY at P2 and P4 (2 waits/K-tile).
// All ds_reads strictly AFTER the phase barrier (race-free, replay-verified).
template <int ACT_GELU, int SPLITK, int SCLQ>
__global__ __launch_bounds__(512, 2) void gemm256_kern(const unsigned short* __restrict__ A,
                                                       const unsigned short* __restrict__ Bt,
                                                       const float* __restrict__ bias,
                                                       unsigned short* __restrict__ C,
                                                       int M, int N, int K){
  __shared__ unsigned short As[2][2][128 * 64];   // [buf][half][row*64+col]
  __shared__ unsigned short Bs[2][2][128 * 64];
  int bid = blockIdx.y * gridDim.x + blockIdx.x;
  const int nwg = gridDim.x * gridDim.y;
  bid = (bid & 7) * (nwg >> 3) + (bid >> 3);            // T1 XCD swizzle (nwg%8==0)
  const int bx = bid % gridDim.x, by = bid / gridDim.x;
  const int m0 = by << 8, n0 = bx << 8;
  const int tid  = threadIdx.x;
  const int wave = tid >> 6, lane = tid & 63;
  const int wr = wave >> 2, wc = wave & 3;              // 2 x 4 wave grid
  const int lr = lane & 15, lk = lane >> 4;
  const int kz   = K / SPLITK;
  const int kbeg = (SPLITK > 1) ? blockIdx.z * kz : 0;
  const int NT   = kz >> 6;                             // K-tiles of 64
  const int srow = tid >> 3;                            // 0..63 (+64 on call 1)
  const int scol = ((tid & 7) ^ (srow & 7)) << 3;       // inverse-swizzled source slot
  const unsigned short* Ag = A  + (size_t)(m0 + srow) * K + kbeg + scol;
  const unsigned short* Bg = Bt + (size_t)(n0 + srow) * K + kbeg + scol;
  const int dst = tid * 8;                              // ushorts (16B/thread)
  const int sk0 = ((    lk) ^ (lr & 7)) << 3;           // kk=0 swizzled slot
  const int sk1 = ((4 + lk) ^ (lr & 7)) << 3;           // kk=1
  const int aro = lr * 64;
  const int bro = ((wc & 1) * 64 + lr) * 64;
  const int bh_ = wc >> 1;

  f32x4 acc[8][4] = {};
  bf16x8 aR[4][2], bR[2][2][2];

  auto stA = [&](int b, int h, int kt){
    const unsigned short* s = Ag + (size_t)(h * 128) * K + kt * 64;
    gl_lds16(s,                  &As[b][h][dst]);
    gl_lds16(s + (size_t)64 * K, &As[b][h][4096 + dst]);
  };
  auto stB = [&](int b, int h, int kt){
    const unsigned short* s = Bg + (size_t)(h * 128) * K + kt * 64;
    gl_lds16(s,                  &Bs[b][h][dst]);
    gl_lds16(s + (size_t)64 * K, &Bs[b][h][4096 + dst]);
  };

#define LOAD_A(b, MH) { \
  _Pragma("unroll") for (int mp = 0; mp < 4; ++mp){ \
    aR[mp][0] = ldfrag(&As[b][wr][aro + ((MH) * 64 + mp * 16) * 64 + sk0]); \
    aR[mp][1] = ldfrag(&As[b][wr][aro + ((MH) * 64 + mp * 16) * 64 + sk1]); } }
#define LOAD_B(b, NH) { \
  _Pragma("unroll") for (int np = 0; np < 2; ++np){ \
    bR[NH][np][0] = ldfrag(&Bs[b][bh_][bro + ((NH) * 32 + np * 16) * 64 + sk0]); \
    bR[NH][np][1] = ldfrag(&Bs[b][bh_][bro + ((NH) * 32 + np * 16) * 64 + sk1]); } }
#define QMFMA(MH, NH) { \
  _Pragma("unroll") for (int kk = 0; kk < 2; ++kk) \
  _Pragma("unroll") for (int mp = 0; mp < 4; ++mp) \
  _Pragma("unroll") for (int np = 0; np < 2; ++np) \
    acc[(MH)*4+mp][(NH)*2+np] = __builtin_amdgcn_mfma_f32_16x16x32_bf16( \
        aR[mp][kk], bR[NH][np][kk], acc[(MH)*4+mp][(NH)*2+np], 0, 0, 0); }
#define PHASE_TAIL(QM) \
  asm volatile("s_barrier" ::: "memory"); \
  asm volatile("s_waitcnt lgkmcnt(0)" ::: "memory"); \
  __builtin_amdgcn_sched_barrier(0); \
  __builtin_amdgcn_s_setprio(1); \
  QM; \
  __builtin_amdgcn_s_setprio(0); \
  __builtin_amdgcn_sched_barrier(0); \
  asm volatile("s_barrier" ::: "memory");

  // prologue: stage tile 0 (order A0,B0,B1,A1), guard A0+B0, sync
  stA(0, 0, 0); stB(0, 0, 0); stB(0, 1, 0); stA(0, 1, 0);
  asm volatile("s_waitcnt vmcnt(4)" ::: "memory");
  asm volatile("s_barrier" ::: "memory");

  for (int t = 0; t < NT; ++t){
    const int b = t & 1, bn = b ^ 1;
    const bool pf = (t + 1 < NT);
    // P1: read A0,B0 (guarded by prev P4's vmcnt); stage A0(t+1); NO wait
    LOAD_A(b, 0); LOAD_B(b, 0);
    if (pf) stA(bn, 0, t + 1);
    PHASE_TAIL(QMFMA(0, 0));
    // P2: read B1; stage B0(t+1); vmcnt(4) lands B1(t)+A1(t)
    LOAD_B(b, 1);
    if (pf){ stB(bn, 0, t + 1); asm volatile("s_waitcnt vmcnt(4)" ::: "memory"); }
    else   {                    asm volatile("s_waitcnt vmcnt(0)" ::: "memory"); }
    PHASE_TAIL(QMFMA(0, 1));
    // P3: read A1 (landed at P2); stage B1(t+1); no wait
    LOAD_A(b, 1);
    if (pf){ stB(bn, 1, t + 1); }
    PHASE_TAIL(QMFMA(1, 0));
    // P4: no reads; stage A1(t+1); vmcnt(4) lands A0',B0' for next P1
    if (pf){ stA(bn, 1, t + 1); asm volatile("s_waitcnt vmcnt(4)" ::: "memory"); }
    PHASE_TAIL(QMFMA(1, 1));
  }
#undef LOAD_A
#undef LOAD_B
#undef QMFMA
#undef PHASE_TAIL

  unsigned short* Cb = C + (SPLITK > 1 ? (size_t)blockIdx.z * M * N : 0);
  float bvv[4], csc[4];
  #pragma unroll
  for (int n = 0; n < 4; ++n){
    const int col = n0 + wc * 64 + n * 16 + lr;
    bvv[n] = (SPLITK == 1) ? bias[col] : 0.0f;
    csc[n] = (SCLQ && col < 1024) ? 0.18033688011112042f : 1.0f;
  }
  #pragma unroll
  for (int m = 0; m < 8; ++m){
    #pragma unroll
    for (int j = 0; j < 4; ++j){
      const int row = m0 + wr * 128 + m * 16 + lk * 4 + j;
      unsigned short* crow = Cb + (size_t)row * N + n0 + wc * 64 + lr;
      #pragma unroll
      for (int n = 0; n < 4; ++n){          // n-inner: 4 adjacent half-line stores
        float v = acc[m][n][j] + bvv[n];
        if (ACT_GELU) v = 0.5f * v * (1.0f + fast_erf(v * 0.70710678118654752f));
        if (SCLQ) v *= csc[n];
        crow[n * 16] = f2b(v);
      }
    }
  }
}

// ===== flash attention v8 (FROZEN): R11 compute + T4 counted-vmcnt 3-buffer =====
__global__ __launch_bounds__(512) void attn_kern(const unsigned short* __restrict__ QKV,
                                                 const unsigned short* __restrict__ Vt,
                                                 const unsigned long long* __restrict__ mbits,
                                                 unsigned short* __restrict__ O){
  __shared__ unsigned short Ks[3][64 * 64];
  __shared__ unsigned short Vs[3][64 * 64];     // [d][t], swizzled
  __shared__ unsigned short Ps[8][16 * 64];     // per-wave P [qrow][key], swizzled
  const int tid = threadIdx.x;
  const int wave = tid >> 6, lane = tid & 63;
  const int lr = lane & 15, lk = lane >> 4;
  // T1 XCD swizzle: nwg = 16*32 = 512; each XCD gets 64 consecutive bids = 4 heads
  int bid = blockIdx.y * gridDim.x + blockIdx.x;
  bid = (bid & 7) * 64 + (bid >> 3);
  const int qblk = bid & 15, bh = bid >> 4;
  const int rowbase = (bh >> 4) * 2048 + (bh & 15) * 128;
  const unsigned short* Qg = QKV + (size_t)rowbase * 3072;
  const unsigned short* Kg = Qg + 1024;
  const unsigned short* Vh = Vt + (size_t)bh * kHD * kS;
  const int qbase = qblk * 128 + wave * 16;
  constexpr int NT = kS / 64;   // 32

  // Q (pre-scaled by 0.125*log2e in the QKV epilogue) as MFMA B-fragment
  bf16x8 qf[2];
  { const int qr = qbase + lr;
    const unsigned short* qp = Qg + (size_t)(qr >> 4) * 3072 + (qr & 15) * 64 + lk * 8;
    qf[0] = ldfrag(qp); qf[1] = ldfrag(qp + 32); }

  f32x4 accO[4] = {};
  float lsum = 0.f;
  unsigned short* Pw = Ps[wave];
  char* Pwb = (char*)Pw + lr * 128 + ((lk & 1) << 3);
  const int lr7 = lr & 7;

  const unsigned long long* mrp = mbits + (size_t)(qbase + lr) * 32;
  unsigned long long mb = mrp[0];

  // prologue: stage tiles 0 and 1; land tile 0 (leave K1,V1 in flight)
  stageK8(Kg, Ks[0], tid, 0);
  stageV8(Vh, Vs[0], tid, 0);
  stageK8(Kg, Ks[1], tid, 64);
  stageV8(Vh, Vs[1], tid, 64);
  asm volatile("s_waitcnt vmcnt(2)" ::: "memory");
  asm volatile("s_barrier" ::: "memory");

  int cur = 0, stg = 2;
  for (int t = 0; t < NT; ++t){
    unsigned long long mbn = 0;
    if (t < NT - 1) mbn = mrp[t + 1];
    if (t < NT - 2){
      stageK8(Kg, Ks[stg], tid, (t + 2) * 64);
      stageV8(Vh, Vs[stg], tid, (t + 2) * 64);
    }
    // QK^T swapped: sa[n][j] = S[key = n*16 + lk*4 + j][qrow = lr] (pre-scaled)
    f32x4 sa[4] = {};
    #pragma unroll
    for (int kk = 0; kk < 2; ++kk)
      #pragma unroll
      for (int n = 0; n < 4; ++n){
        bf16x8 kf = ld_swz(Ks[cur], n * 16 + lr, kk * 4 + lk);
        sa[n] = __builtin_amdgcn_mfma_f32_16x16x32_bf16(kf, qf[kk], sa[n], 0, 0, 0);
      }
    const unsigned wb = (unsigned)(mb >> (lk * 16));
    float s = 0.f;
    #pragma unroll
    for (int n = 0; n < 4; ++n){
      float p0, p1, p2, p3;
      {
        float v0 = fexp2(sa[n][0]), v1 = fexp2(sa[n][1]);
        float v2 = fexp2(sa[n][2]), v3 = fexp2(sa[n][3]);
        const int s0 = ((int)(wb << (31 - (n * 4 + 0)))) >> 31;
        const int s1 = ((int)(wb << (31 - (n * 4 + 1)))) >> 31;
        const int s2 = ((int)(wb << (31 - (n * 4 + 2)))) >> 31;
        const int s3 = ((int)(wb << (31 - (n * 4 + 3)))) >> 31;
        p0 = __builtin_bit_cast(float, __builtin_bit_cast(int, v0) & s0);
        p1 = __builtin_bit_cast(float, __builtin_bit_cast(int, v1) & s1);
        p2 = __builtin_bit_cast(float, __builtin_bit_cast(int, v2) & s2);
        p3 = __builtin_bit_cast(float, __builtin_bit_cast(int, v3) & s3);
      }
      s += (p0 + p1) + (p2 + p3);
      unsigned r0, r1;
      asm("v_cvt_pk_bf16_f32 %0, %1, %2" : "=v"(r0) : "v"(p0), "v"(p1));
      asm("v_cvt_pk_bf16_f32 %0, %1, %2" : "=v"(r1) : "v"(p2), "v"(p3));
      *(uint2*)(Pwb + (((2 * n + (lk >> 1)) ^ lr7) << 4)) = make_uint2(r0, r1);
    }
    s += __shfl_xor(s, 16);
    s += __shfl_xor(s, 32);
    lsum += s;
    #pragma unroll
    for (int kk = 0; kk < 2; ++kk){
      bf16x8 pf = ld_swz(Pw, lr, kk * 4 + lk);
      #pragma unroll
      for (int dd = 0; dd < 4; ++dd){
        bf16x8 vfr = ld_swz(Vs[cur], dd * 16 + lr, kk * 4 + lk);
        accO[dd] = __builtin_amdgcn_mfma_f32_16x16x32_bf16(pf, vfr, accO[dd], 0, 0, 0);
      }
    }
    mb = mbn;
    if (t < NT - 2){
      asm volatile("s_waitcnt vmcnt(3)" ::: "memory");   // lands K,V(t+1)
    } else if (t < NT - 1){
      asm volatile("s_waitcnt vmcnt(1)" ::: "memory");   // lands K,V(NT-1)
    }
    if (t < NT - 1) asm volatile("s_barrier" ::: "memory");
    cur = (cur == 2) ? 0 : cur + 1;
    stg = (stg == 2) ? 0 : stg + 1;
  }
  const size_t hoff = (size_t)bh * kS * kHD;
  #pragma unroll
  for (int j = 0; j < 4; ++j){
    const float inv = 1.0f / __shfl(lsum, lk * 4 + j);
    const int row = qbase + lk * 4 + j;
    #pragma unroll
    for (int dd = 0; dd < 4; ++dd)
      O[hoff + (size_t)row * 64 + dd * 16 + lr] = f2b(accO[dd][j] * inv);
  }
}

// ------- fused split-K reduce + bias + residual add + LayerNorm -----------------
template <int NP, int PBF16, int OUT_B>
__global__ __launch_bounds__(256) void add_ln_kern(const float* __restrict__ X,
                                                   const void* __restrict__ P,
                                                   const float* __restrict__ bias,
                                                   const float* __restrict__ g,
                                                   const float* __restrict__ be,
                                                   float* __restrict__ Yf,
                                                   unsigned short* __restrict__ Yb){
  const int row = blockIdx.x;
  const int tid = threadIdx.x;
  const size_t pstride = (size_t)kTOK * kD;
  const int idx = row * 256 + tid;
  float r0 = 0.f, r1 = 0.f, r2 = 0.f, r3 = 0.f;
  #pragma unroll
  for (int z = 0; z < NP; ++z){
    if (PBF16){
      ushort4 u = ((const ushort4*)P)[z * (pstride / 4) + idx];
      r0 += b2f(u.x); r1 += b2f(u.y); r2 += b2f(u.z); r3 += b2f(u.w);
    } else {
      float4 p = ((const float4*)P)[z * (pstride / 4) + idx];
      r0 += p.x; r1 += p.y; r2 += p.z; r3 += p.w;
    }
  }
  const float4 bb = ((const float4*)bias)[tid];
  const float4 xv = ((const float4*)X)[idx];
  const float a0 = xv.x + r0 + bb.x, a1 = xv.y + r1 + bb.y;
  const float a2 = xv.z + r2 + bb.z, a3 = xv.w + r3 + bb.w;
  float s = a0 + a1 + a2 + a3;
  float q = a0*a0 + a1*a1 + a2*a2 + a3*a3;
  #pragma unroll
  for (int d = 1; d < 64; d <<= 1){ s += __shfl_xor(s, d); q += __shfl_xor(q, d); }
  __shared__ float red[8];
  const int wave = tid >> 6, lane = tid & 63;
  if (lane == 0){ red[wave] = s; red[4 + wave] = q; }
  __syncthreads();
  s = red[0] + red[1] + red[2] + red[3];
  q = red[4] + red[5] + red[6] + red[7];
  const float mu   = s * (1.0f / kD);
  const float var  = q * (1.0f / kD) - mu * mu;
  const float rstd = rsqrtf(var + 1e-5f);
  const float4 gv = ((const float4*)g)[tid];
  const float4 bv = ((const float4*)be)[tid];
  const float y0 = (a0 - mu) * rstd * gv.x + bv.x;
  const float y1 = (a1 - mu) * rstd * gv.y + bv.y;
  const float y2 = (a2 - mu) * rstd * gv.z + bv.z;
  const float y3 = (a3 - mu) * rstd * gv.w + bv.w;
  ((float4*)Yf)[idx] = make_float4(y0, y1, y2, y3);
  if (OUT_B)
    ((ushort4*)Yb)[idx] = make_ushort4(f2b(y0), f2b(y1), f2b(y2), f2b(y3));
}

} // namespace

extern "C" void kernel_launch(void* const* d_in, const int* in_sizes, int n_in,
                              void* d_out, int out_size, void* d_ws, size_t ws_size,
                              hipStream_t stream){
  (void)in_sizes; (void)n_in; (void)out_size;
  const float* x   = (const float*)d_in[0];
  const int*   mask= (const int*)d_in[1];
  const float* Wq  = (const float*)d_in[2];  const float* bq  = (const float*)d_in[3];
  const float* Wk  = (const float*)d_in[4];  const float* bk  = (const float*)d_in[5];
  const float* Wv  = (const float*)d_in[6];  const float* bv  = (const float*)d_in[7];
  const float* Wo  = (const float*)d_in[8];  const float* bo  = (const float*)d_in[9];
  const float* W1  = (const float*)d_in[10]; const float* b1  = (const float*)d_in[11];
  const float* W2  = (const float*)d_in[12]; const float* b2  = (const float*)d_in[13];
  const float* g1  = (const float*)d_in[14]; const float* be1 = (const float*)d_in[15];
  const float* g2  = (const float*)d_in[16]; const float* be2 = (const float*)d_in[17];

  char* ws = (char*)d_ws;
  const size_t MB = 1024 * 1024;
  if (ws_size < 96 * MB) return;   // need 96 MB of scratch

  // Layout (stage-by-stage lifetime-checked):
  unsigned short* W2T   = (unsigned short*)(ws + 0 * MB);    //  8 MB  preamble -> W2
  unsigned short* W1T   = (unsigned short*)(ws + 8 * MB);    //  8 MB  preamble -> W1
  unsigned short* WqkvT = (unsigned short*)(ws + 16 * MB);   //  6 MB  preamble -> QKV
  unsigned short* WoT   = (unsigned short*)(ws + 22 * MB);   //  2 MB  preamble -> Wo
  unsigned short* xb    = (unsigned short*)(ws + 24 * MB);   //  8 MB  preamble -> QKV
  unsigned short* qkv   = (unsigned short*)(ws + 32 * MB);   // 24 MB  QKV -> attn
  unsigned short* vt    = (unsigned short*)(ws + 56 * MB);   //  8 MB  vtrans -> attn
  unsigned short* av    = (unsigned short*)(ws + 64 * MB);   //  8 MB  attn -> Wo
  unsigned long long* mbits = (unsigned long long*)(ws + 72 * MB);     // 512 KB -> attn
  float* bqkv           = (float*)(ws + 80 * MB);            // 12 KB  preamble -> QKV
  // aliases (lifetimes checked): mbits/bqkv dead after attn/QKV respectively.
  unsigned short* woP   = (unsigned short*)(ws + 32 * MB);   // 32 MB [4][4096][1024] bf16, Wo -> LN1
  float* y32            = (float*)(ws + 72 * MB);            // 16 MB LN1 -> LN2 (over mbits+bqkv, dead)
  unsigned short* yb    = (unsigned short*)(ws + 88 * MB);   //  8 MB LN1 -> W1
  unsigned short* hb    = (unsigned short*)(ws + 40 * MB);   // 32 MB W1 -> W2 (over woP tail+vt+av, dead)
  unsigned short* w2p   = (unsigned short*)(ws + 8 * MB);    // 32 MB [4][4096][1024] bf16, W2 -> LN2

  dim3 blk(256), gblk(512);
  wtrans_all_kern<<<dim3(12288), blk, 0, stream>>>(Wq, Wk, Wv, Wo, W1, W2,
                                                   WqkvT, WoT, W1T, W2T);
  prep_misc_kern<<<dim3(20492), blk, 0, stream>>>(x, xb, mask, mbits, bq, bk, bv, bqkv);

  // fused QKV projection: [4096][3072]; Q columns pre-scaled by 0.125*log2(e)
  gemm256_kern<0,1,1><<<dim3(12, 16), gblk, 0, stream>>>(xb, WqkvT, bqkv, qkv, 4096, 3072, 1024);

  vtrans_kern<<<dim3(32, 32), blk, 0, stream>>>(qkv, vt);
  attn_kern<<<dim3(16, 32), gblk, 0, stream>>>(qkv, vt, mbits, av);

  // Wo projection, split-K x4 -> bf16 partials; LN1 fuses reduce + bo + residual(x)
  gemm256_kern<0,4,0><<<dim3(4, 16, 4), gblk, 0, stream>>>(av, WoT, bo, woP, 4096, 1024, 1024);
  add_ln_kern<4,1,1><<<dim3(4096), blk, 0, stream>>>(x, woP, bo, g1, be1, y32, yb);

  // FFN
  gemm256_kern<1,1,0><<<dim3(16, 16), gblk, 0, stream>>>(yb, W1T, b1, hb, 4096, 4096, 1024);
  // W2, split-K x4 -> bf16 partials; LN2 fuses reduce + b2 + residual(y32)
  gemm256_kern<0,4,0><<<dim3(4, 16, 4), gblk, 0, stream>>>(hb, W2T, b2, w2p, 4096, 1024, 4096);
  add_ln_kern<4,1,0><<<dim3(4096), blk, 0, stream>>>(y32, w2p, b2, g2, be2, (float*)d_out, nullptr);
}

// Round 18
// 227.123 us; speedup vs baseline: 1.1365x; 1.0362x over previous
//
#include <hip/hip_runtime.h>
#include <cstdint>
#include <cstddef>

namespace {

constexpr int kS  = 2048;   // sequence
constexpr int kD  = 1024;   // model dim
constexpr int kHD = 64;     // head dim
constexpr int kTOK = 4096;  // B * S rows

typedef float f32x4 __attribute__((ext_vector_type(4)));
typedef __bf16 bf16x8 __attribute__((ext_vector_type(8)));
typedef unsigned short u16x8 __attribute__((ext_vector_type(8)));

__device__ __forceinline__ unsigned short f2b(float f){
  unsigned int u = __builtin_bit_cast(unsigned int, f);
  u += 0x7fffu + ((u >> 16) & 1u);      // RNE
  return (unsigned short)(u >> 16);
}

__device__ __forceinline__ float b2f(unsigned short u){
  return __builtin_bit_cast(float, (unsigned)u << 16);
}

__device__ __forceinline__ bf16x8 ldfrag(const unsigned short* p){
  return __builtin_bit_cast(bf16x8, *(const u16x8*)p);
}

__device__ __forceinline__ float fexp2(float x){
#if __has_builtin(__builtin_amdgcn_exp2f)
  return __builtin_amdgcn_exp2f(x);
#else
  return exp2f(x);
#endif
}

// erf via Abramowitz-Stegun 7.1.26 (|eps| <= 1.5e-7, far below bf16 resolution)
__device__ __forceinline__ float fast_erf(float x){
  const float ax = fabsf(x);
#if __has_builtin(__builtin_amdgcn_rcpf)
  const float t = __builtin_amdgcn_rcpf(1.0f + 0.3275911f * ax);
#else
  const float t = 1.0f / (1.0f + 0.3275911f * ax);
#endif
  const float y = t * (0.254829592f + t * (-0.284496736f + t * (1.421413741f +
                  t * (-1.453152027f + t * 1.061405429f))));
  const float e = fexp2(-ax * ax * 1.4426950408889634f);
  return copysignf(1.0f - y * e, x);
}

__device__ __forceinline__ void gl_lds16(const void* g, void* l){
  // async global->LDS, 16B per lane; LDS dest is wave-uniform base + lane*16
  __builtin_amdgcn_global_load_lds(
      (__attribute__((address_space(1))) void*)(void*)g,
      (__attribute__((address_space(3))) void*)l, 16, 0, 0);
}

// swizzled 16B fragment read from a 64-col bf16 tile: slot in [0,8)
__device__ __forceinline__ bf16x8 ld_swz(const unsigned short* tile, int row, int slot){
  return ldfrag(tile + row * 64 + (((slot ^ row) & 7) << 3));
}

// 512-thread staging of one 64-row K tile from fused QKV (head-block mapping)
__device__ __forceinline__ void stageK8(const unsigned short* Kg, unsigned short* lds,
                                        int tid, int t0){
  const int r = tid >> 3, sl = tid & 7;        // row 0..63, 16B slot 0..7
  const int sabs = t0 + r;
  gl_lds16(Kg + (size_t)(sabs >> 4) * 3072 + (sabs & 15) * 64 + (((sl ^ r) & 7) << 3),
           (char*)lds + tid * 16);
}

// 512-thread staging of a 64x64 slice of Vt [64][kS] (cols t0..t0+64)
__device__ __forceinline__ void stageV8(const unsigned short* Vh, unsigned short* lds,
                                        int tid, int t0){
  const int r = tid >> 3, sl = tid & 7;
  gl_lds16(Vh + (size_t)r * kS + t0 + (((sl ^ r) & 7) << 3),
           (char*)lds + tid * 16);
}

// ---------- merged preamble: wtrans (12288 blk) | cvt/maskbits/catbias (20492) --
__global__ __launch_bounds__(256) void prep_all_kern(const float* __restrict__ Wq,
                                                     const float* __restrict__ Wk,
                                                     const float* __restrict__ Wv,
                                                     const float* __restrict__ Wo,
                                                     const float* __restrict__ W1,
                                                     const float* __restrict__ W2,
                                                     unsigned short* __restrict__ WqkvT,
                                                     unsigned short* __restrict__ WoT,
                                                     unsigned short* __restrict__ W1T,
                                                     unsigned short* __restrict__ W2T,
                                                     const float* __restrict__ x,
                                                     unsigned short* __restrict__ xb,
                                                     const int* __restrict__ mask,
                                                     unsigned long long* __restrict__ mb,
                                                     const float* __restrict__ bq,
                                                     const float* __restrict__ bk,
                                                     const float* __restrict__ bv,
                                                     float* __restrict__ bqkv){
  const int blk = blockIdx.x;
  if (blk < 12288){
    // ---- weight transpose+convert: 6 jobs by block range
    const int b = blk;
    const float* W; unsigned short* Wt; int K, N, nx, lb;
    if      (b < 1024){ W = Wq; Wt = WqkvT;                 K = 1024; N = 1024; nx = 32;  lb = b; }
    else if (b < 2048){ W = Wk; Wt = WqkvT + 1024 * 1024;   K = 1024; N = 1024; nx = 32;  lb = b - 1024; }
    else if (b < 3072){ W = Wv; Wt = WqkvT + 2048 * 1024;   K = 1024; N = 1024; nx = 32;  lb = b - 2048; }
    else if (b < 4096){ W = Wo; Wt = WoT;                   K = 1024; N = 1024; nx = 32;  lb = b - 3072; }
    else if (b < 8192){ W = W1; Wt = W1T;                   K = 1024; N = 4096; nx = 128; lb = b - 4096; }
    else              { W = W2; Wt = W2T;                   K = 4096; N = 1024; nx = 32;  lb = b - 8192; }
    __shared__ float t[32][33];
    const int n0 = (lb % nx) * 32, k0 = (lb / nx) * 32;
    const int tx = threadIdx.x & 31, ty = threadIdx.x >> 5;   // ty in [0,8)
    #pragma unroll
    for (int i = 0; i < 32; i += 8)
      t[ty + i][tx] = W[(size_t)(k0 + ty + i) * N + n0 + tx];
    __syncthreads();
    #pragma unroll
    for (int i = 0; i < 32; i += 8)
      Wt[(size_t)(n0 + ty + i) * K + k0 + tx] = f2b(t[tx][ty + i]);
  } else {
    const int b = blk - 12288;
    if (b < 4096){
      const int i = b * 256 + threadIdx.x;
      float4 v = ((const float4*)x)[i];
      ((ushort4*)xb)[i] = make_ushort4(f2b(v.x), f2b(v.y), f2b(v.z), f2b(v.w));
    } else if (b < 20480){
      const int gw   = ((b - 4096) * 256 + threadIdx.x) >> 6;
      const int lane = threadIdx.x & 63;
      const int row  = gw >> 5, word = gw & 31;
      const int key  = ((lane >> 2) & 3) * 16 + ((lane >> 4) & 3) * 4 + (lane & 3);
      const int m = mask[(size_t)row * kS + word * 64 + key];
      const unsigned long long bl = __ballot(m != 0);
      if (lane == 0) mb[(size_t)row * 32 + word] = bl;
    } else {
      const int i = (b - 20480) * 256 + threadIdx.x;
      float v = (i < 1024) ? bq[i] : ((i < 2048) ? bk[i - 1024] : bv[i - 2048]);
      bqkv[i] = v;
    }
  }
}

// ---------------- V slice of fused QKV -> Vt [bh][64][kS] (bf16 transpose) -------
__global__ __launch_bounds__(256) void vtrans_kern(const unsigned short* __restrict__ QKV,
                                                   unsigned short* __restrict__ Vt){
  __shared__ unsigned short t[64][65];
  int bh = blockIdx.y, s0 = blockIdx.x * 64;
  const int rowbase = (bh >> 4) * 2048 + (bh & 15) * 128;
  const unsigned short* Vg = QKV + (size_t)rowbase * 3072 + 2048;
  unsigned short* Vth = Vt + (size_t)bh * kHD * kS;
  int tx = threadIdx.x & 63, ty = threadIdx.x >> 6;   // ty in [0,4)
  #pragma unroll
  for (int i = 0; i < 64; i += 4){
    const int s = s0 + ty + i;
    t[ty + i][tx] = Vg[(size_t)(s >> 4) * 3072 + (s & 15) * 64 + tx];
  }
  __syncthreads();
  #pragma unroll
  for (int i = 0; i < 64; i += 4)
    Vth[(size_t)(ty + i) * kS + s0 + tx] = t[tx][ty + i];
}

// ===== GEMM v7 (Round-14 verified, 230.2us): 256x256, BK=64, 2-phase schedule ===
// 2 phases per K-tile, ONE barrier per phase, all ds_reads strictly AFTER the
// barrier (validation + graph-replay verified at R14).
// Ledger (4 loads staged per phase; invariant 4 outstanding entering each phase):
//   P1: stage {A0',B0'} (8 out) -> vmcnt(4) lands A1(t),B1(t) -> barrier ->
//       reads A0,B0,B1 -> 32 MFMA (quadrants (0,0),(0,1)).
//   P2: stage {A1',B1'} (8 out) -> vmcnt(4) lands A0',B0' -> barrier ->
//       read A1 -> 32 MFMA (quadrants (1,0),(1,1)).
//   Prologue: stage A0,B0,A1,B1 of tile0, vmcnt(4) lands A0,B0.
//   Last tile: vmcnt(0) at P1, none at P2.
template <int ACT_GELU, int SPLITK, int SCLQ>
__global__ __launch_bounds__(512, 2) void gemm256_kern(const unsigned short* __restrict__ A,
                                                       const unsigned short* __restrict__ Bt,
                                                       const float* __restrict__ bias,
                                                       unsigned short* __restrict__ C,
                                                       int M, int N, int K){
  __shared__ unsigned short As[2][2][128 * 64];   // [buf][half][row*64+col]
  __shared__ unsigned short Bs[2][2][128 * 64];
  int bid = blockIdx.y * gridDim.x + blockIdx.x;
  const int nwg = gridDim.x * gridDim.y;
  bid = (bid & 7) * (nwg >> 3) + (bid >> 3);            // T1 XCD swizzle (nwg%8==0)
  const int bx = bid % gridDim.x, by = bid / gridDim.x;
  const int m0 = by << 8, n0 = bx << 8;
  const int tid  = threadIdx.x;
  const int wave = tid >> 6, lane = tid & 63;
  const int wr = wave >> 2, wc = wave & 3;              // 2 x 4 wave grid
  const int lr = lane & 15, lk = lane >> 4;
  const int kz   = K / SPLITK;
  const int kbeg = (SPLITK > 1) ? blockIdx.z * kz : 0;
  const int NT   = kz >> 6;                             // K-tiles of 64
  const int srow = tid >> 3;                            // 0..63 (+64 on call 1)
  const int scol = ((tid & 7) ^ (srow & 7)) << 3;       // inverse-swizzled source slot
  const unsigned short* Ag = A  + (size_t)(m0 + srow) * K + kbeg + scol;
  const unsigned short* Bg = Bt + (size_t)(n0 + srow) * K + kbeg + scol;
  const int dst = tid * 8;                              // ushorts (16B/thread)
  const int sk0 = ((    lk) ^ (lr & 7)) << 3;           // kk=0 swizzled slot
  const int sk1 = ((4 + lk) ^ (lr & 7)) << 3;           // kk=1
  const int aro = lr * 64;
  const int bro = ((wc & 1) * 64 + lr) * 64;
  const int bh_ = wc >> 1;

  f32x4 acc[8][4] = {};
  bf16x8 aR[4][2], bR[2][2][2];

  auto stA = [&](int b, int h, int kt){
    const unsigned short* s = Ag + (size_t)(h * 128) * K + kt * 64;
    gl_lds16(s,                  &As[b][h][dst]);
    gl_lds16(s + (size_t)64 * K, &As[b][h][4096 + dst]);
  };
  auto stB = [&](int b, int h, int kt){
    const unsigned short* s = Bg + (size_t)(h * 128) * K + kt * 64;
    gl_lds16(s,                  &Bs[b][h][dst]);
    gl_lds16(s + (size_t)64 * K, &Bs[b][h][4096 + dst]);
  };

#define LOAD_A(b, MH) { \
  _Pragma("unroll") for (int mp = 0; mp < 4; ++mp){ \
    aR[mp][0] = ldfrag(&As[b][wr][aro + ((MH) * 64 + mp * 16) * 64 + sk0]); \
    aR[mp][1] = ldfrag(&As[b][wr][aro + ((MH) * 64 + mp * 16) * 64 + sk1]); } }
#define LOAD_B(b, NH) { \
  _Pragma("unroll") for (int np = 0; np < 2; ++np){ \
    bR[NH][np][0] = ldfrag(&Bs[b][bh_][bro + ((NH) * 32 + np * 16) * 64 + sk0]); \
    bR[NH][np][1] = ldfrag(&Bs[b][bh_][bro + ((NH) * 32 + np * 16) * 64 + sk1]); } }
#define QMFMA(MH, NH) { \
  _Pragma("unroll") for (int kk = 0; kk < 2; ++kk) \
  _Pragma("unroll") for (int mp = 0; mp < 4; ++mp) \
  _Pragma("unroll") for (int np = 0; np < 2; ++np) \
    acc[(MH)*4+mp][(NH)*2+np] = __builtin_amdgcn_mfma_f32_16x16x32_bf16( \
        aR[mp][kk], bR[NH][np][kk], acc[(MH)*4+mp][(NH)*2+np], 0, 0, 0); }

  // prologue: stage tile 0 in ledger order {A0,B0} then {A1,B1}; land A0,B0
  stA(0, 0, 0); stB(0, 0, 0);
  stA(0, 1, 0); stB(0, 1, 0);
  asm volatile("s_waitcnt vmcnt(4)" ::: "memory");

  for (int t = 0; t < NT; ++t){
    const int b = t & 1, bn = b ^ 1;
    const bool pf = (t + 1 < NT);
    // ---- P1: stage {A0',B0'}; land A1(t),B1(t); reads A0,B0,B1; MFMA (0,0),(0,1)
    if (pf){ stA(bn, 0, t + 1); stB(bn, 0, t + 1);
             asm volatile("s_waitcnt vmcnt(4)" ::: "memory"); }
    else   { asm volatile("s_waitcnt vmcnt(0)" ::: "memory"); }
    asm volatile("s_barrier" ::: "memory");
    LOAD_A(b, 0);
    LOAD_B(b, 0);
    LOAD_B(b, 1);
    __builtin_amdgcn_s_setprio(1);
    QMFMA(0, 0);
    QMFMA(0, 1);
    __builtin_amdgcn_s_setprio(0);
    // ---- P2: stage {A1',B1'}; land A0',B0'; reads A1; MFMA (1,0),(1,1)
    if (pf){ stA(bn, 1, t + 1); stB(bn, 1, t + 1);
             asm volatile("s_waitcnt vmcnt(4)" ::: "memory"); }
    asm volatile("s_barrier" ::: "memory");
    LOAD_A(b, 1);
    __builtin_amdgcn_s_setprio(1);
    QMFMA(1, 0);
    QMFMA(1, 1);
    __builtin_amdgcn_s_setprio(0);
  }
#undef LOAD_A
#undef LOAD_B
#undef QMFMA

  unsigned short* Cb = C + (SPLITK > 1 ? (size_t)blockIdx.z * M * N : 0);
  float bvv[4], csc[4];
  #pragma unroll
  for (int n = 0; n < 4; ++n){
    const int col = n0 + wc * 64 + n * 16 + lr;
    bvv[n] = (SPLITK == 1) ? bias[col] : 0.0f;
    csc[n] = (SCLQ && col < 1024) ? 0.18033688011112042f : 1.0f;
  }
  #pragma unroll
  for (int m = 0; m < 8; ++m){
    #pragma unroll
    for (int j = 0; j < 4; ++j){
      const int row = m0 + wr * 128 + m * 16 + lk * 4 + j;
      unsigned short* crow = Cb + (size_t)row * N + n0 + wc * 64 + lr;
      #pragma unroll
      for (int n = 0; n < 4; ++n){          // n-inner: 4 adjacent half-line stores
        float v = acc[m][n][j] + bvv[n];
        if (ACT_GELU) v = 0.5f * v * (1.0f + fast_erf(v * 0.70710678118654752f));
        if (SCLQ) v *= csc[n];
        crow[n * 16] = f2b(v);
      }
    }
  }
}

// ===== flash attention v8 (FROZEN): R11 compute + T4 counted-vmcnt 3-buffer =====
__global__ __launch_bounds__(512) void attn_kern(const unsigned short* __restrict__ QKV,
                                                 const unsigned short* __restrict__ Vt,
                                                 const unsigned long long* __restrict__ mbits,
                                                 unsigned short* __restrict__ O){
  __shared__ unsigned short Ks[3][64 * 64];
  __shared__ unsigned short Vs[3][64 * 64];     // [d][t], swizzled
  __shared__ unsigned short Ps[8][16 * 64];     // per-wave P [qrow][key], swizzled
  const int tid = threadIdx.x;
  const int wave = tid >> 6, lane = tid & 63;
  const int lr = lane & 15, lk = lane >> 4;
  // T1 XCD swizzle: nwg = 16*32 = 512; each XCD gets 64 consecutive bids = 4 heads
  int bid = blockIdx.y * gridDim.x + blockIdx.x;
  bid = (bid & 7) * 64 + (bid >> 3);
  const int qblk = bid & 15, bh = bid >> 4;
  const int rowbase = (bh >> 4) * 2048 + (bh & 15) * 128;
  const unsigned short* Qg = QKV + (size_t)rowbase * 3072;
  const unsigned short* Kg = Qg + 1024;
  const unsigned short* Vh = Vt + (size_t)bh * kHD * kS;
  const int qbase = qblk * 128 + wave * 16;
  constexpr int NT = kS / 64;   // 32

  // Q (pre-scaled by 0.125*log2e in the QKV epilogue) as MFMA B-fragment
  bf16x8 qf[2];
  { const int qr = qbase + lr;
    const unsigned short* qp = Qg + (size_t)(qr >> 4) * 3072 + (qr & 15) * 64 + lk * 8;
    qf[0] = ldfrag(qp); qf[1] = ldfrag(qp + 32); }

  f32x4 accO[4] = {};
  float lsum = 0.f;
  unsigned short* Pw = Ps[wave];
  char* Pwb = (char*)Pw + lr * 128 + ((lk & 1) << 3);
  const int lr7 = lr & 7;

  const unsigned long long* mrp = mbits + (size_t)(qbase + lr) * 32;
  unsigned long long mb = mrp[0];

  // prologue: stage tiles 0 and 1; land tile 0 (leave K1,V1 in flight)
  stageK8(Kg, Ks[0], tid, 0);
  stageV8(Vh, Vs[0], tid, 0);
  stageK8(Kg, Ks[1], tid, 64);
  stageV8(Vh, Vs[1], tid, 64);
  asm volatile("s_waitcnt vmcnt(2)" ::: "memory");
  asm volatile("s_barrier" ::: "memory");

  int cur = 0, stg = 2;
  for (int t = 0; t < NT; ++t){
    unsigned long long mbn = 0;
    if (t < NT - 1) mbn = mrp[t + 1];
    if (t < NT - 2){
      stageK8(Kg, Ks[stg], tid, (t + 2) * 64);
      stageV8(Vh, Vs[stg], tid, (t + 2) * 64);
    }
    // QK^T swapped: sa[n][j] = S[key = n*16 + lk*4 + j][qrow = lr] (pre-scaled)
    f32x4 sa[4] = {};
    #pragma unroll
    for (int kk = 0; kk < 2; ++kk)
      #pragma unroll
      for (int n = 0; n < 4; ++n){
        bf16x8 kf = ld_swz(Ks[cur], n * 16 + lr, kk * 4 + lk);
        sa[n] = __builtin_amdgcn_mfma_f32_16x16x32_bf16(kf, qf[kk], sa[n], 0, 0, 0);
      }
    const unsigned wb = (unsigned)(mb >> (lk * 16));
    float s = 0.f;
    #pragma unroll
    for (int n = 0; n < 4; ++n){
      float p0, p1, p2, p3;
      {
        float v0 = fexp2(sa[n][0]), v1 = fexp2(sa[n][1]);
        float v2 = fexp2(sa[n][2]), v3 = fexp2(sa[n][3]);
        const int s0 = ((int)(wb << (31 - (n * 4 + 0)))) >> 31;
        const int s1 = ((int)(wb << (31 - (n * 4 + 1)))) >> 31;
        const int s2 = ((int)(wb << (31 - (n * 4 + 2)))) >> 31;
        const int s3 = ((int)(wb << (31 - (n * 4 + 3)))) >> 31;
        p0 = __builtin_bit_cast(float, __builtin_bit_cast(int, v0) & s0);
        p1 = __builtin_bit_cast(float, __builtin_bit_cast(int, v1) & s1);
        p2 = __builtin_bit_cast(float, __builtin_bit_cast(int, v2) & s2);
        p3 = __builtin_bit_cast(float, __builtin_bit_cast(int, v3) & s3);
      }
      s += (p0 + p1) + (p2 + p3);
      unsigned r0, r1;
      asm("v_cvt_pk_bf16_f32 %0, %1, %2" : "=v"(r0) : "v"(p0), "v"(p1));
      asm("v_cvt_pk_bf16_f32 %0, %1, %2" : "=v"(r1) : "v"(p2), "v"(p3));
      *(uint2*)(Pwb + (((2 * n + (lk >> 1)) ^ lr7) << 4)) = make_uint2(r0, r1);
    }
    s += __shfl_xor(s, 16);
    s += __shfl_xor(s, 32);
    lsum += s;
    #pragma unroll
    for (int kk = 0; kk < 2; ++kk){
      bf16x8 pf = ld_swz(Pw, lr, kk * 4 + lk);
      #pragma unroll
      for (int dd = 0; dd < 4; ++dd){
        bf16x8 vfr = ld_swz(Vs[cur], dd * 16 + lr, kk * 4 + lk);
        accO[dd] = __builtin_amdgcn_mfma_f32_16x16x32_bf16(pf, vfr, accO[dd], 0, 0, 0);
      }
    }
    mb = mbn;
    if (t < NT - 2){
      asm volatile("s_waitcnt vmcnt(3)" ::: "memory");   // lands K,V(t+1)
    } else if (t < NT - 1){
      asm volatile("s_waitcnt vmcnt(1)" ::: "memory");   // lands K,V(NT-1)
    }
    if (t < NT - 1) asm volatile("s_barrier" ::: "memory");
    cur = (cur == 2) ? 0 : cur + 1;
    stg = (stg == 2) ? 0 : stg + 1;
  }
  const size_t hoff = (size_t)bh * kS * kHD;
  #pragma unroll
  for (int j = 0; j < 4; ++j){
    const float inv = 1.0f / __shfl(lsum, lk * 4 + j);
    const int row = qbase + lk * 4 + j;
    #pragma unroll
    for (int dd = 0; dd < 4; ++dd)
      O[hoff + (size_t)row * 64 + dd * 16 + lr] = f2b(accO[dd][j] * inv);
  }
}

// ------- fused split-K reduce + bias + residual add + LayerNorm -----------------
template <int NP, int PBF16, int OUT_B>
__global__ __launch_bounds__(256) void add_ln_kern(const float* __restrict__ X,
                                                   const void* __restrict__ P,
                                                   const float* __restrict__ bias,
                                                   const float* __restrict__ g,
                                                   const float* __restrict__ be,
                                                   float* __restrict__ Yf,
                                                   unsigned short* __restrict__ Yb){
  const int row = blockIdx.x;
  const int tid = threadIdx.x;
  const size_t pstride = (size_t)kTOK * kD;
  const int idx = row * 256 + tid;
  float r0 = 0.f, r1 = 0.f, r2 = 0.f, r3 = 0.f;
  #pragma unroll
  for (int z = 0; z < NP; ++z){
    if (PBF16){
      ushort4 u = ((const ushort4*)P)[z * (pstride / 4) + idx];
      r0 += b2f(u.x); r1 += b2f(u.y); r2 += b2f(u.z); r3 += b2f(u.w);
    } else {
      float4 p = ((const float4*)P)[z * (pstride / 4) + idx];
      r0 += p.x; r1 += p.y; r2 += p.z; r3 += p.w;
    }
  }
  const float4 bb = ((const float4*)bias)[tid];
  const float4 xv = ((const float4*)X)[idx];
  const float a0 = xv.x + r0 + bb.x, a1 = xv.y + r1 + bb.y;
  const float a2 = xv.z + r2 + bb.z, a3 = xv.w + r3 + bb.w;
  float s = a0 + a1 + a2 + a3;
  float q = a0*a0 + a1*a1 + a2*a2 + a3*a3;
  #pragma unroll
  for (int d = 1; d < 64; d <<= 1){ s += __shfl_xor(s, d); q += __shfl_xor(q, d); }
  __shared__ float red[8];
  const int wave = tid >> 6, lane = tid & 63;
  if (lane == 0){ red[wave] = s; red[4 + wave] = q; }
  __syncthreads();
  s = red[0] + red[1] + red[2] + red[3];
  q = red[4] + red[5] + red[6] + red[7];
  const float mu   = s * (1.0f / kD);
  const float var  = q * (1.0f / kD) - mu * mu;
  const float rstd = rsqrtf(var + 1e-5f);
  const float4 gv = ((const float4*)g)[tid];
  const float4 bv = ((const float4*)be)[tid];
  const float y0 = (a0 - mu) * rstd * gv.x + bv.x;
  const float y1 = (a1 - mu) * rstd * gv.y + bv.y;
  const float y2 = (a2 - mu) * rstd * gv.z + bv.z;
  const float y3 = (a3 - mu) * rstd * gv.w + bv.w;
  ((float4*)Yf)[idx] = make_float4(y0, y1, y2, y3);
  if (OUT_B)
    ((ushort4*)Yb)[idx] = make_ushort4(f2b(y0), f2b(y1), f2b(y2), f2b(y3));
}

} // namespace

extern "C" void kernel_launch(void* const* d_in, const int* in_sizes, int n_in,
                              void* d_out, int out_size, void* d_ws, size_t ws_size,
                              hipStream_t stream){
  (void)in_sizes; (void)n_in; (void)out_size;
  const float* x   = (const float*)d_in[0];
  const int*   mask= (const int*)d_in[1];
  const float* Wq  = (const float*)d_in[2];  const float* bq  = (const float*)d_in[3];
  const float* Wk  = (const float*)d_in[4];  const float* bk  = (const float*)d_in[5];
  const float* Wv  = (const float*)d_in[6];  const float* bv  = (const float*)d_in[7];
  const float* Wo  = (const float*)d_in[8];  const float* bo  = (const float*)d_in[9];
  const float* W1  = (const float*)d_in[10]; const float* b1  = (const float*)d_in[11];
  const float* W2  = (const float*)d_in[12]; const float* b2  = (const float*)d_in[13];
  const float* g1  = (const float*)d_in[14]; const float* be1 = (const float*)d_in[15];
  const float* g2  = (const float*)d_in[16]; const float* be2 = (const float*)d_in[17];

  char* ws = (char*)d_ws;
  const size_t MB = 1024 * 1024;
  if (ws_size < 96 * MB) return;   // need 96 MB of scratch

  // Layout (stage-by-stage lifetime-checked):
  unsigned short* W2T   = (unsigned short*)(ws + 0 * MB);    //  8 MB  preamble -> W2
  unsigned short* W1T   = (unsigned short*)(ws + 8 * MB);    //  8 MB  preamble -> W1
  unsigned short* WqkvT = (unsigned short*)(ws + 16 * MB);   //  6 MB  preamble -> QKV
  unsigned short* WoT   = (unsigned short*)(ws + 22 * MB);   //  2 MB  preamble -> Wo
  unsigned short* xb    = (unsigned short*)(ws + 24 * MB);   //  8 MB  preamble -> QKV
  unsigned short* qkv   = (unsigned short*)(ws + 32 * MB);   // 24 MB  QKV -> attn
  unsigned short* vt    = (unsigned short*)(ws + 56 * MB);   //  8 MB  vtrans -> attn
  unsigned short* av    = (unsigned short*)(ws + 64 * MB);   //  8 MB  attn -> Wo
  unsigned long long* mbits = (unsigned long long*)(ws + 72 * MB);     // 512 KB -> attn
  float* bqkv           = (float*)(ws + 80 * MB);            // 12 KB  preamble -> QKV
  // aliases (lifetimes checked): mbits/bqkv dead after attn/QKV respectively.
  unsigned short* woP   = (unsigned short*)(ws + 32 * MB);   // 32 MB [4][4096][1024] bf16, Wo -> LN1
  float* y32            = (float*)(ws + 72 * MB);            // 16 MB LN1 -> LN2 (over mbits+bqkv, dead)
  unsigned short* yb    = (unsigned short*)(ws + 88 * MB);   //  8 MB LN1 -> W1
  unsigned short* hb    = (unsigned short*)(ws + 40 * MB);   // 32 MB W1 -> W2 (over woP tail+vt+av, dead)
  unsigned short* w2p   = (unsigned short*)(ws + 8 * MB);    // 32 MB [4][4096][1024] bf16, W2 -> LN2

  dim3 blk(256), gblk(512);
  prep_all_kern<<<dim3(32780), blk, 0, stream>>>(Wq, Wk, Wv, Wo, W1, W2,
                                                 WqkvT, WoT, W1T, W2T,
                                                 x, xb, mask, mbits, bq, bk, bv, bqkv);

  // fused QKV projection: [4096][3072]; Q columns pre-scaled by 0.125*log2(e)
  gemm256_kern<0,1,1><<<dim3(12, 16), gblk, 0, stream>>>(xb, WqkvT, bqkv, qkv, 4096, 3072, 1024);

  vtrans_kern<<<dim3(32, 32), blk, 0, stream>>>(qkv, vt);
  attn_kern<<<dim3(16, 32), gblk, 0, stream>>>(qkv, vt, mbits, av);

  // Wo projection, split-K x4 -> bf16 partials; LN1 fuses reduce + bo + residual(x)
  gemm256_kern<0,4,0><<<dim3(4, 16, 4), gblk, 0, stream>>>(av, WoT, bo, woP, 4096, 1024, 1024);
  add_ln_kern<4,1,1><<<dim3(4096), blk, 0, stream>>>(x, woP, bo, g1, be1, y32, yb);

  // FFN
  gemm256_kern<1,1,0><<<dim3(16, 16), gblk, 0, stream>>>(yb, W1T, b1, hb, 4096, 4096, 1024);
  // W2, split-K x4 -> bf16 partials; LN2 fuses reduce + b2 + residual(y32)
  gemm256_kern<0,4,0><<<dim3(4, 16, 4), gblk, 0, stream>>>(hb, W2T, b2, w2p, 4096, 1024, 4096);
  add_ln_kern<4,1,0><<<dim3(4096), blk, 0, stream>>>(y32, w2p, b2, g2, be2, (float*)d_out, nullptr);
}